// Round 8
// baseline (190.345 us; speedup 1.0000x reference)
//
#include <hip/hip_runtime.h>
#include <hip/hip_bf16.h>

typedef __bf16 bf16_t;
typedef __bf16 bf16x2 __attribute__((ext_vector_type(2)));
typedef __bf16 bf16x4 __attribute__((ext_vector_type(4)));
typedef __bf16 bf16x8 __attribute__((ext_vector_type(8)));
typedef float  f32x4  __attribute__((ext_vector_type(4)));

#define MFMA16(A,B,C) __builtin_amdgcn_mfma_f32_16x16x32_bf16((A),(B),(C),0,0,0)

constexpr int Bn = 2, Cc = 128;
constexpr int N  = 4096;         // tokens per batch
constexpr int T  = Bn * N;       // 8192 tokens total
constexpr int D  = 2 * Cc;       // 256 = [real | imag] channels
constexpr int NSP = 4;           // key splits
constexpr float EPS = 1e-5f;
constexpr float SCL = 0.08838834764831845f * 1.4426950408889634f; // C^-0.5*log2e, folded into Q

// 64-row x 256-ch bf16 A/B tile (32 KB), fragment-ordered:
//   frag = (ch>>5)*4 + (row>>4); lane = ((ch>>3)&3)*16 + (row&15); elem = ch&7
__device__ __forceinline__ int tfrag(int row, int ch) {
    return (((ch >> 5) * 4 + (row >> 4)) << 10) +
           ((((ch >> 3) & 3) * 16 + (row & 15)) << 4) + (ch & 7) * 2;
}
// K tile: 32 keys x 256 ch (16 KB), frags 16keys x 32ch (A-operand for S^T)
__device__ __forceinline__ int kfrag32(int key, int ch) {
    return (((ch >> 5) * 2 + (key >> 4)) << 10) +
           ((((ch >> 3) & 3) * 16 + (key & 15)) << 4) + (ch & 7) * 2;
}
// V tile (A-operand for O^T): 256 ch x 32 keys, k-slot PERMUTED to match the
// natural register layout of P^T exiting the S^T MFMA:
//   k-slot u = (key>>4)*4 + (key&3), quad chunk q = (key&15)>>2
__device__ __forceinline__ int vfragP(int ch, int key) {
    return ((ch >> 4) << 10) +
           (((((key & 15) >> 2) * 16) + (ch & 15)) << 4) +
           (((key >> 4) * 4 + (key & 3)) << 1);
}

__device__ __forceinline__ void gl16(const void* g, void* l) {
    __builtin_amdgcn_global_load_lds(
        (const __attribute__((address_space(1))) void*)g,
        (__attribute__((address_space(3))) void*)l, 16, 0, 0);
}

__device__ __forceinline__ float4 finalize_ssl(const float4* part, const float* bn_w,
                                               const float* bn_b, int c) {
    float4 p0 = part[c * 4 + 0], p1 = part[c * 4 + 1];
    float4 p2 = part[c * 4 + 2], p3 = part[c * 4 + 3];
    float sr = p0.x + p1.x + p2.x + p3.x, si = p0.y + p1.y + p2.y + p3.y;
    float qr = p0.z + p1.z + p2.z + p3.z, qi = p0.w + p1.w + p2.w + p3.w;
    const float inv = 1.0f / (float)(Bn * N);
    float mr = sr * inv, mi = si * inv;
    float vr = qr * inv - mr * mr, vi = qi * inv - mi * mi;
    float scr = bn_w[c * 2 + 0] * rsqrtf(vr + EPS);
    float sci = bn_w[c * 2 + 1] * rsqrtf(vi + EPS);
    return make_float4(scr, bn_b[c * 2 + 0] - mr * scr,
                       sci, bn_b[c * 2 + 1] - mi * sci);
}

// ---- kernel 1: fused BN partial stats (blocks 0..511) + weight prep --------
__global__ void k_pre(const float* __restrict__ x, float4* __restrict__ part,
                      const float* __restrict__ wq, const float* __restrict__ wk,
                      const float* __restrict__ wv, const float* __restrict__ bq,
                      const float* __restrict__ bk, const float* __restrict__ bv,
                      char* __restrict__ Wg, float* __restrict__ bt) {
    int tid = threadIdx.x;
    if (blockIdx.x < 512) {
        int bid = blockIdx.x;            // q*128 + c
        int q = bid >> 7, c = bid & 127;
        float sr = 0.f, si = 0.f, qr = 0.f, qi = 0.f;
        for (int b = 0; b < Bn; ++b) {
            const float2* p = (const float2*)x + (size_t)(b * Cc + c) * N + q * 1024;
            for (int i = tid; i < 1024; i += 256) {
                float2 v = p[i];
                sr += v.x; si += v.y; qr += v.x * v.x; qi += v.y * v.y;
            }
        }
        #pragma unroll
        for (int d = 32; d >= 1; d >>= 1) {
            sr += __shfl_xor(sr, d); si += __shfl_xor(si, d);
            qr += __shfl_xor(qr, d); qi += __shfl_xor(qi, d);
        }
        __shared__ float red[4][4];
        int w = tid >> 6;
        if ((tid & 63) == 0) { red[w][0] = sr; red[w][1] = si; red[w][2] = qr; red[w][3] = qi; }
        __syncthreads();
        if (tid == 0) {
            part[c * 4 + q] = make_float4(red[0][0] + red[1][0] + red[2][0] + red[3][0],
                                          red[0][1] + red[1][1] + red[2][1] + red[3][1],
                                          red[0][2] + red[1][2] + red[2][2] + red[3][2],
                                          red[0][3] + red[1][3] + red[2][3] + red[3][3]);
        }
    } else {
        int o = blockIdx.x - 512;        // 768 = [Qr Qi Kr Ki Vr Vi] x128
        int k = tid;
        int proj = o >> 8, oc = o & 255;
        const float* wsrc = proj == 0 ? wq : (proj == 1 ? wk : wv);
        const float* bsrc = proj == 0 ? bq : (proj == 1 ? bk : bv);
        int co = oc >> 7, oo = oc & 127;
        int c = k & 127, kc = k >> 7;
        float val;
        if (co == 0) val = (kc == 0) ? wsrc[(oo * 128 + c) * 2 + 0] : -wsrc[(oo * 128 + c) * 2 + 1];
        else         val = (kc == 0) ? wsrc[(oo * 128 + c) * 2 + 1] :  wsrc[(oo * 128 + c) * 2 + 0];
        float fs = (proj == 0) ? SCL : 1.0f;   // fold softmax scale into Q
        int tile = o >> 6, row = o & 63;
        *(bf16_t*)(Wg + (size_t)tile * 32768 + tfrag(row, k)) = (bf16_t)(val * fs);
        if (k == 0) bt[o] = bsrc[oo * 2 + co] * fs;
    }
}

// ---- kernel 2: fused normalize + QKV GEMM ---------------------------------
__global__ __launch_bounds__(256) void k_qkv(const float* __restrict__ x,
        const float4* __restrict__ part, const float* __restrict__ bn_w,
        const float* __restrict__ bn_b, const char* __restrict__ Wg,
        const float* __restrict__ bt,
        char* __restrict__ Qg, char* __restrict__ Kg, char* __restrict__ Vg) {
    __shared__ __align__(16) char Xsh[32768];
    __shared__ __align__(16) char Wsh[32768];
    __shared__ float4 ssl[128];
    int mx = blockIdx.x, ny = blockIdx.y;   // 128 x 12
    int tid = threadIdx.x;
    int w = tid >> 6, lane = tid & 63, n15 = lane & 15, quad = lane >> 4;
    const char* wsp = Wg + (size_t)ny * 32768;
    #pragma unroll
    for (int i = 0; i < 8; ++i) {
        int off = (w * 8 + i) * 1024 + lane * 16;
        gl16(wsp + off, Wsh + off);
    }
    if (tid < 128) ssl[tid] = finalize_ssl(part, bn_w, bn_b, tid);
    __syncthreads();
    int b = mx >> 6, hw0 = (mx & 63) * 64;
    const float2* xin = (const float2*)x;
    #pragma unroll
    for (int it = 0; it < 16; ++it) {
        int idx = it * 256 + tid;
        int cp = idx >> 6, hw = idx & 63;
        size_t gi = (size_t)(b * Cc + cp * 2) * N + hw0 + hw;
        float2 v0 = xin[gi], v1 = xin[gi + N];
        float4 s0 = ssl[cp * 2], s1 = ssl[cp * 2 + 1];
        bf16x2 pr, pi;
        pr[0] = (bf16_t)(v0.x * s0.x + s0.y); pr[1] = (bf16_t)(v1.x * s1.x + s1.y);
        pi[0] = (bf16_t)(v0.y * s0.z + s0.w); pi[1] = (bf16_t)(v1.y * s1.z + s1.w);
        *(bf16x2*)(Xsh + tfrag(hw, cp * 2))       = pr;
        *(bf16x2*)(Xsh + tfrag(hw, cp * 2 + 128)) = pi;
    }
    __syncthreads();
    f32x4 acc[4] = {};
    #pragma unroll
    for (int ks = 0; ks < 8; ++ks) {
        bf16x8 a = *(const bf16x8*)(Xsh + (ks * 4 + w) * 1024 + lane * 16);
        #pragma unroll
        for (int t = 0; t < 4; ++t) {
            bf16x8 bw = *(const bf16x8*)(Wsh + (ks * 4 + t) * 1024 + lane * 16);
            acc[t] = MFMA16(a, bw, acc[t]);
        }
    }
    int proj = ny >> 2;            // 0=Q 1=K 2=V
    int jb = (ny & 3) * 64;
    #pragma unroll
    for (int t = 0; t < 4; ++t) {
        int j = jb + t * 16 + n15;
        float bias = bt[ny * 64 + t * 16 + n15];
        #pragma unroll
        for (int r = 0; r < 4; ++r) {
            int tk = mx * 64 + w * 16 + quad * 4 + r;
            float v = acc[t][r] + bias;
            int bb = tk >> 12, n = tk & (N - 1);
            if (proj == 0) {
                *(bf16_t*)(Qg + (size_t)(tk >> 6) * 32768 + tfrag(tk & 63, j)) = (bf16_t)v;
            } else {
                size_t tb = (size_t)(bb * 128 + (n >> 5)) * 16384;
                if (proj == 1) *(bf16_t*)(Kg + tb + kfrag32(n & 31, j)) = (bf16_t)v;
                else           *(bf16_t*)(Vg + tb + vfragP(j, n & 31)) = (bf16_t)v;
            }
        }
    }
}

// ---- kernel 3: flash attention (S^T / O^T form) + fused split-combine ------
// Wave (r,h): S^T = K(h-half keys) x Q(rows r*32..): keys on quad axis ->
// P^T packs with ds_write_b64 straight into the PV B-fragment. O^T = V x P^T.
// Prefetch issued right after barS. Last of 4 split-blocks combines + writes out.
__global__ __launch_bounds__(256, 2) void k_attn(const char* __restrict__ Qg,
        const char* __restrict__ Kg, const char* __restrict__ Vg,
        bf16_t* __restrict__ Opb, float* __restrict__ Lp, unsigned* __restrict__ cnt,
        const float4* __restrict__ part, const float* __restrict__ bn_w,
        const float* __restrict__ bn_b, const float* __restrict__ x,
        const float* __restrict__ gamma, float* __restrict__ out) {
    __shared__ __align__(16) char smem[69632];
    int bid = blockIdx.x;               // 512 = b(2) x sp(4) x qt(64)
    int qt = bid & 63, sp = (bid >> 6) & 3, b = bid >> 8;
    int tid = threadIdx.x;
    int w = tid >> 6, lane = tid & 63, n15 = lane & 15, quad = lane >> 4;
    int r = w >> 1, h = w & 1;
    char* KshB = smem;                  // 2 x 16 KB
    char* VshB = smem + 32768;          // 2 x 16 KB
    char* Pb   = smem + 65536;          // 4 KB (P^T, B-frag image, 64r x 32k)

    bf16x8 qf[2][8];                    // B-operand: rows qt*64 + r*32 + g*16
    const char* qb = Qg + (size_t)(b * 64 + qt) * 32768;
    #pragma unroll
    for (int g = 0; g < 2; ++g)
        #pragma unroll
        for (int ks = 0; ks < 8; ++ks)
            qf[g][ks] = *(const bf16x8*)(qb + (ks * 4 + r * 2 + g) * 1024 + lane * 16);

    bf16x8 onev;                        // ones A-fragment (for l^T row sums)
    #pragma unroll
    for (int j = 0; j < 8; ++j) onev[j] = (bf16_t)1.0f;

    f32x4 o[2][8] = {};                 // O^T: ch-half h (8 tiles) x rows 32
    f32x4 l2[2] = {};

    int tbase = b * 128 + sp * 32;
    {   // prologue: stage tile 0 -> buffer 0
        const char* kb = Kg + (size_t)tbase * 16384;
        const char* vb = Vg + (size_t)tbase * 16384;
        #pragma unroll
        for (int i = 0; i < 4; ++i) {
            int off = (w * 4 + i) * 1024 + lane * 16;
            gl16(kb + off, KshB + off);
            gl16(vb + off, VshB + off);
        }
    }
    for (int kt = 0; kt < 32; ++kt) {
        int p = kt & 1;
        __syncthreads();                // barS: tile kt landed; bufs kt-1 free
        if (kt < 31) {                  // prefetch kt+1 NOW (drains across QK at barP)
            const char* kb = Kg + (size_t)(tbase + kt + 1) * 16384;
            const char* vb = Vg + (size_t)(tbase + kt + 1) * 16384;
            int pb = (p ^ 1) * 16384;
            #pragma unroll
            for (int i = 0; i < 4; ++i) {
                int off = (w * 4 + i) * 1024 + lane * 16;
                gl16(kb + off, KshB + pb + off);
                gl16(vb + off, VshB + pb + off);
            }
        }
        const char* Ksh = KshB + p * 16384;
        const char* Vsh = VshB + p * 16384;
        // S^T: A = K (keys h*16.., m-axis), B = Q rows (n-axis)
        f32x4 s[2] = {};
        #pragma unroll
        for (int ks = 0; ks < 8; ++ks) {
            bf16x8 kf = *(const bf16x8*)(Ksh + (ks * 2 + h) * 1024 + lane * 16);
            s[0] = MFMA16(kf, qf[0][ks], s[0]);
            s[1] = MFMA16(kf, qf[1][ks], s[1]);
        }
        // P^T = exp2(S^T): lane holds keys h*16+quad*4+ri for row g*16+n15
        // -> one b64 write per g lands in B-frag slot (lane*16 + h*8)
        #pragma unroll
        for (int g = 0; g < 2; ++g) {
            bf16x4 pk;
            #pragma unroll
            for (int ri = 0; ri < 4; ++ri)
                pk[ri] = (bf16_t)__builtin_amdgcn_exp2f(s[g][ri]);
            *(bf16x4*)(Pb + (r * 2 + g) * 1024 + lane * 16 + h * 8) = pk;
        }
        __syncthreads();                // barP: P^T complete (prefetch drains here)
        bf16x8 pb0 = *(const bf16x8*)(Pb + (r * 2 + 0) * 1024 + lane * 16);
        bf16x8 pb1 = *(const bf16x8*)(Pb + (r * 2 + 1) * 1024 + lane * 16);
        l2[0] = MFMA16(onev, pb0, l2[0]);
        l2[1] = MFMA16(onev, pb1, l2[1]);
        #pragma unroll
        for (int ct = 0; ct < 8; ++ct) {
            bf16x8 vf = *(const bf16x8*)(Vsh + (h * 8 + ct) * 1024 + lane * 16);
            o[0][ct] = MFMA16(vf, pb0, o[0][ct]);
            o[1][ct] = MFMA16(vf, pb1, o[1][ct]);
        }
    }
    // epilogue: O^T C-layout -> token fixed per lane, 4 consecutive ch packed
    #pragma unroll
    for (int g = 0; g < 2; ++g) {
        int token = b * N + qt * 64 + r * 32 + g * 16 + n15;
        #pragma unroll
        for (int ct = 0; ct < 8; ++ct) {
            bf16x4 ov;
            #pragma unroll
            for (int ri = 0; ri < 4; ++ri) ov[ri] = (bf16_t)o[g][ct][ri];
            *(bf16x4*)(Opb + ((size_t)sp * T + token) * D + h * 128 + ct * 16 + quad * 4) = ov;
        }
        if (h == 0 && quad == 0)
            Lp[sp * T + b * N + qt * 64 + r * 32 + g * 16 + n15] = l2[g][0];
    }
    // ---- fused combine: last of the 4 split-blocks for (b,qt) finishes -----
    __syncthreads();
    int* flagp = (int*)(smem + 68864);
    if (tid == 0) {
        __threadfence();                            // release Opb/Lp device-wide
        unsigned old = atomicAdd(&cnt[b * 64 + qt], 1u);
        *flagp = (old == 3u);
    }
    __syncthreads();
    if (!*flagp) return;
    __threadfence();                                // acquire other splits' writes

    float* Ot   = (float*)smem;                     // [256 ch][65] pitch
    float4* ssl = (float4*)(smem + 66560);          // 2 KB
    float* wts  = (float*)(smem + 68608);           // 64 floats
    int tok0 = b * N + qt * 64;
    if (tid < 128) ssl[tid] = finalize_ssl(part, bn_w, bn_b, tid);
    if (tid < 64) {
        float Z = 0.f;
        #pragma unroll
        for (int s = 0; s < NSP; ++s) Z += Lp[s * T + tok0 + tid];
        wts[tid] = gamma[0] / Z;
    }
    __syncthreads();
    #pragma unroll
    for (int i = 0; i < 8; ++i) {
        int idx = i * 256 + tid;                    // 2048 = 64 tok x 32 chunks
        int tok = idx & 63, chunk = idx >> 6;
        size_t base = (size_t)(tok0 + tok) * D + chunk * 8;
        float acc[8] = {};
        #pragma unroll
        for (int s = 0; s < NSP; ++s) {
            bf16x8 v = *(const bf16x8*)(Opb + (size_t)s * T * D + base);
            #pragma unroll
            for (int j = 0; j < 8; ++j) acc[j] += (float)v[j];
        }
        float ww = wts[tok];
        #pragma unroll
        for (int j = 0; j < 8; ++j) Ot[(chunk * 8 + j) * 65 + tok] = acc[j] * ww;
    }
    __syncthreads();
    const float2* xin = (const float2*)x;
    float2* xo = (float2*)out;
    #pragma unroll
    for (int i = 0; i < 32; ++i) {
        int linear = i * 256 + tid;                 // 8192 = 128 c x 64 hw
        int c = linear >> 6, hw = linear & 63;
        size_t idx = (size_t)(b * Cc + c) * N + qt * 64 + hw;
        float2 v = xin[idx];
        float4 sc = ssl[c];
        float2 res;
        res.x = v.x * sc.x + sc.y + Ot[c * 65 + hw];
        res.y = v.y * sc.z + sc.w + Ot[(128 + c) * 65 + hw];
        xo[idx] = res;
    }
}

extern "C" void kernel_launch(void* const* d_in, const int* in_sizes, int n_in,
                              void* d_out, int out_size, void* d_ws, size_t ws_size,
                              hipStream_t stream) {
    const float* x    = (const float*)d_in[0];
    const float* bn_w = (const float*)d_in[1];
    const float* bn_b = (const float*)d_in[2];
    const float* wq   = (const float*)d_in[3];
    const float* bq   = (const float*)d_in[4];
    const float* wk   = (const float*)d_in[5];
    const float* bk   = (const float*)d_in[6];
    const float* wv   = (const float*)d_in[7];
    const float* bv   = (const float*)d_in[8];
    const float* gam  = (const float*)d_in[9];
    float* out = (float*)d_out;

    char* ws = (char*)d_ws;
    size_t off = 0;
    auto alloc = [&](size_t bytes) -> void* {
        void* p = ws + off;
        off += (bytes + 255) & ~(size_t)255;
        return p;
    };
    float4*   part = (float4*)alloc(512 * sizeof(float4));
    char*     Wg   = (char*)alloc((size_t)12 * 32768);
    float*    bt   = (float*)alloc(768 * 4);
    char*     Qg   = (char*)alloc((size_t)128 * 32768);
    char*     Kg   = (char*)alloc((size_t)256 * 16384);
    char*     Vg   = (char*)alloc((size_t)256 * 16384);
    bf16_t*   Opb  = (bf16_t*)alloc((size_t)NSP * T * D * 2);
    float*    Lp   = (float*)alloc((size_t)NSP * T * 4);
    unsigned* cnt  = (unsigned*)alloc(512);

    hipMemsetAsync(cnt, 0, 512, stream);
    k_pre<<<1280, 256, 0, stream>>>(x, part, wq, wk, wv, bq, bk, bv, Wg, bt);
    k_qkv<<<dim3(128, 12), 256, 0, stream>>>(x, part, bn_w, bn_b, Wg, bt, Qg, Kg, Vg);
    k_attn<<<512, 256, 0, stream>>>(Qg, Kg, Vg, Opb, Lp, cnt,
                                    part, bn_w, bn_b, x, gam, out);
}